// Round 1
// baseline (271.411 us; speedup 1.0000x reference)
//
#include <hip/hip_runtime.h>
#include <hip/hip_bf16.h>
#include <cstdint>

// ---------- types ----------
typedef __attribute__((ext_vector_type(4))) float f32x4;
typedef __attribute__((ext_vector_type(8))) __bf16 bf16x8;

#define SCALE_Q 0.08838834764831845f  /* 1/sqrt(128) */

__device__ __forceinline__ short bf16b(float f) {
  unsigned u = __builtin_bit_cast(unsigned, f);
  unsigned r = (u + 0x7fffu + ((u >> 16) & 1u)) >> 16;
  return (short)r;
}

__device__ __forceinline__ f32x4 mfma16(bf16x8 a, bf16x8 b, f32x4 c) {
  return __builtin_amdgcn_mfma_f32_16x16x32_bf16(a, b, c, 0, 0, 0);
}

__device__ __forceinline__ void async16(void* lds, const void* g) {
  __builtin_amdgcn_global_load_lds(
      (const __attribute__((address_space(1))) unsigned int*)g,
      (__attribute__((address_space(3))) unsigned int*)lds, 16, 0, 0);
}

// ---------- kernel 1: fp32 -> bf16 for queries/keys/values ----------
__global__ void cvt_x(const float* __restrict__ q, const float* __restrict__ k,
                      const float* __restrict__ v, short* __restrict__ out) {
  const float* src = (blockIdx.y == 0) ? q : (blockIdx.y == 1 ? k : v);
  short* dst = out + (size_t)blockIdx.y * 8388608;
  size_t i = (size_t)blockIdx.x * 256 + threadIdx.x;
  float4 f = reinterpret_cast<const float4*>(src)[i];
  short4 o;
  o.x = bf16b(f.x); o.y = bf16b(f.y); o.z = bf16b(f.z); o.w = bf16b(f.w);
  reinterpret_cast<short4*>(dst)[i] = o;
}

// ---------- kernel 2: transpose + convert weights -> WT[z][N][K] bf16 ----------
// z=0: Wq (scaled by 1/sqrt(E)), z=1: Wk, z=2: Wv, z=3: Wo
__global__ void cvt_w(const float* __restrict__ Wq, const float* __restrict__ Wk,
                      const float* __restrict__ Wv, const float* __restrict__ Wo,
                      short* __restrict__ out) {
  int z = blockIdx.z;
  const float* W = (z == 0) ? Wq : (z == 1) ? Wk : (z == 2) ? Wv : Wo;
  float scale = (z == 0) ? SCALE_Q : 1.0f;
  __shared__ float t[64][65];
  int n0 = blockIdx.x * 64, k0 = blockIdx.y * 64;
  int c = threadIdx.x & 63, r0 = threadIdx.x >> 6;
#pragma unroll
  for (int rr = 0; rr < 16; ++rr) {
    int r = rr * 4 + r0;
    t[r][c] = W[(size_t)(k0 + r) * 1024 + n0 + c];
  }
  __syncthreads();
  short* dst = out + (size_t)z * 1048576;
#pragma unroll
  for (int rr = 0; rr < 16; ++rr) {
    int r = rr * 4 + r0;
    dst[(size_t)(n0 + r) * 1024 + k0 + c] = bf16b(t[c][r] * scale);
  }
}

// ---------- shared GEMM mainloop: C[128x128] += A[128xK] * B^T[128xK]^T ----------
// m97 structure: BK=64, global_load_lds w16, linear LDS, 2x2 waves of 64x64.
__device__ __forceinline__ void gemm_core(const short* A, const short* Bn, int m0,
                                          int n0, short* As, short* Bs,
                                          f32x4 acc[4][4]) {
  int tid = threadIdx.x;
  int lane = tid & 63, wave = tid >> 6;
  int wr = wave >> 1, wc = wave & 1, l15 = lane & 15, lg = lane >> 4;
  for (int k0 = 0; k0 < 1024; k0 += 64) {
#pragma unroll
    for (int i = 0; i < 4; ++i) {
      int r = (tid >> 3) + i * 32, cb = (tid & 7) * 16;
      async16((char*)As + i * 4096 + tid * 16,
              (const char*)A + ((size_t)(m0 + r) * 1024 + k0) * 2 + cb);
      async16((char*)Bs + i * 4096 + tid * 16,
              (const char*)Bn + ((size_t)(n0 + r) * 1024 + k0) * 2 + cb);
    }
    __syncthreads();
#pragma unroll
    for (int kk = 0; kk < 2; ++kk) {
      bf16x8 a[4], b[4];
#pragma unroll
      for (int mt = 0; mt < 4; ++mt)
        a[mt] = *(const bf16x8*)&As[(wr * 64 + mt * 16 + l15) * 64 + lg * 8 + kk * 32];
#pragma unroll
      for (int nt = 0; nt < 4; ++nt)
        b[nt] = *(const bf16x8*)&Bs[(wc * 64 + nt * 16 + l15) * 64 + lg * 8 + kk * 32];
#pragma unroll
      for (int mt = 0; mt < 4; ++mt)
#pragma unroll
        for (int nt = 0; nt < 4; ++nt)
          acc[mt][nt] = mfma16(a[mt], b[nt], acc[mt][nt]);
    }
    __syncthreads();
  }
}

// ---------- kernel 3: QKV projection GEMMs (z selects q/k/v) ----------
// Epilogue layouts: Q [bh][l][e]; K [bh][s][e] with e-index XOR-swizzle;
// Vt [bh][e][s] with s-index XOR-swizzle (pre-swizzled global = T2 via rule 21).
__global__ __launch_bounds__(256, 2) void gemm_qkv(
    const short* __restrict__ X3, const short* __restrict__ WT,
    const float* __restrict__ bq, const float* __restrict__ bk,
    const float* __restrict__ bv, short* __restrict__ Qg, short* __restrict__ Kg,
    short* __restrict__ Vtg) {
  __shared__ short As[8192], Bs[8192];
  int z = blockIdx.z;
  const short* A = X3 + (size_t)z * 8388608;
  const short* Bn = WT + (size_t)z * 1048576;
  const float* bias = (z == 0) ? bq : (z == 1) ? bk : bv;
  float bscale = (z == 0) ? SCALE_Q : 1.0f;
  int m0 = blockIdx.y * 128, n0 = blockIdx.x * 128;
  f32x4 acc[4][4];
#pragma unroll
  for (int mt = 0; mt < 4; ++mt)
#pragma unroll
    for (int nt = 0; nt < 4; ++nt) acc[mt][nt] = f32x4{0.f, 0.f, 0.f, 0.f};
  gemm_core(A, Bn, m0, n0, As, Bs, acc);
  int lane = threadIdx.x & 63, wave = threadIdx.x >> 6;
  int wr = wave >> 1, wc = wave & 1, l15 = lane & 15, lg = lane >> 4;
#pragma unroll
  for (int mt = 0; mt < 4; ++mt)
#pragma unroll
    for (int nt = 0; nt < 4; ++nt) {
      int n = n0 + wc * 64 + nt * 16 + l15;
      float bb = bias[n] * bscale;
#pragma unroll
      for (int j = 0; j < 4; ++j) {
        int m = m0 + wr * 64 + mt * 16 + lg * 4 + j;
        short o = bf16b(acc[mt][nt][j] + bb);
        int s_ = m & 2047, b_ = m >> 11, h_ = n >> 7, e_ = n & 127;
        size_t bh = (size_t)b_ * 8 + h_;
        if (z == 0)
          Qg[(bh * 2048 + s_) * 128 + e_] = o;
        else if (z == 1)
          Kg[(bh * 2048 + s_) * 128 + (e_ ^ ((s_ & 7) << 3))] = o;
        else
          Vtg[(bh * 128 + e_) * 2048 + (s_ ^ ((e_ & 7) << 3))] = o;
      }
    }
}

// ---------- kernel 4: flash attention ----------
// 4 waves x 32 q-rows (QBLK=128), KVBLK=64, E=128. K/Vt staged by
// global_load_lds from pre-swizzled global; reads apply the same XOR.
__global__ __launch_bounds__(256, 2) void attn(const short* __restrict__ Qg,
                                               const short* __restrict__ Kg,
                                               const short* __restrict__ Vtg,
                                               short* __restrict__ Ctx) {
  __shared__ short Ks[8192];  // [64 s][128 e] swizzled
  __shared__ short Vs[8192];  // [128 e][64 s] swizzled
  __shared__ short Ps[8192];  // per-wave [32 q][64 s] swizzled
  int tid = threadIdx.x, lane = tid & 63, wave = tid >> 6;
  int l15 = lane & 15, lg = lane >> 4;
  int bh = blockIdx.y, qb = blockIdx.x;
  int qbase = qb * 128 + wave * 32;
  const short* Qp = Qg + (size_t)bh * 2048 * 128;
  const char* Kbase = (const char*)(Kg + (size_t)bh * 2048 * 128);
  const char* Vbase = (const char*)(Vtg + (size_t)bh * 128 * 2048);

  bf16x8 qa[2][4];
#pragma unroll
  for (int mt = 0; mt < 2; ++mt) {
    int q = qbase + mt * 16 + l15;
#pragma unroll
    for (int kk = 0; kk < 4; ++kk)
      qa[mt][kk] = *(const bf16x8*)&Qp[(size_t)q * 128 + lg * 8 + kk * 32];
  }
  f32x4 acc[2][8];
  float mrun[2][4], lrun[2][4];
#pragma unroll
  for (int mt = 0; mt < 2; ++mt) {
#pragma unroll
    for (int nte = 0; nte < 8; ++nte) acc[mt][nte] = f32x4{0.f, 0.f, 0.f, 0.f};
#pragma unroll
    for (int j = 0; j < 4; ++j) { mrun[mt][j] = -1e30f; lrun[mt][j] = 0.f; }
  }

  for (int s0 = 0; s0 < 2048; s0 += 64) {
#pragma unroll
    for (int i = 0; i < 4; ++i)
      async16((char*)Ks + i * 4096 + tid * 16,
              Kbase + (size_t)s0 * 256 + i * 4096 + tid * 16);
#pragma unroll
    for (int i = 0; i < 4; ++i) {
      int e = (tid >> 3) + i * 32;
      async16((char*)Vs + i * 4096 + tid * 16,
              Vbase + (size_t)e * 4096 + s0 * 2 + (tid & 7) * 16);
    }
    __syncthreads();

    // QK^T: scores 32q x 64s per wave (B-frags shared across both m-tiles)
    f32x4 sc[2][4];
#pragma unroll
    for (int mt = 0; mt < 2; ++mt)
#pragma unroll
      for (int nt = 0; nt < 4; ++nt) sc[mt][nt] = f32x4{0.f, 0.f, 0.f, 0.f};
#pragma unroll
    for (int nt = 0; nt < 4; ++nt) {
      int srow = nt * 16 + l15;
      int sx = (srow & 7) << 3;
#pragma unroll
      for (int kk = 0; kk < 4; ++kk) {
        bf16x8 kb = *(const bf16x8*)&Ks[srow * 128 + ((lg * 8 + kk * 32) ^ sx)];
        sc[0][nt] = mfma16(qa[0][kk], kb, sc[0][nt]);
        sc[1][nt] = mfma16(qa[1][kk], kb, sc[1][nt]);
      }
    }

    // online softmax (rows live on 16-lane column groups; reduce via shfl_xor)
    short* Pw = Ps + wave * 2048;
#pragma unroll
    for (int mt = 0; mt < 2; ++mt) {
#pragma unroll
      for (int j = 0; j < 4; ++j) {
        float mx = fmaxf(fmaxf(sc[mt][0][j], sc[mt][1][j]),
                         fmaxf(sc[mt][2][j], sc[mt][3][j]));
        mx = fmaxf(mx, __shfl_xor(mx, 1));
        mx = fmaxf(mx, __shfl_xor(mx, 2));
        mx = fmaxf(mx, __shfl_xor(mx, 4));
        mx = fmaxf(mx, __shfl_xor(mx, 8));
        float mn = fmaxf(mrun[mt][j], mx);
        float sf = __expf(mrun[mt][j] - mn);
        mrun[mt][j] = mn;
        float rs = 0.f;
#pragma unroll
        for (int nt = 0; nt < 4; ++nt) {
          float p = __expf(sc[mt][nt][j] - mn);
          sc[mt][nt][j] = p;
          rs += p;
        }
        rs += __shfl_xor(rs, 1);
        rs += __shfl_xor(rs, 2);
        rs += __shfl_xor(rs, 4);
        rs += __shfl_xor(rs, 8);
        lrun[mt][j] = lrun[mt][j] * sf + rs;
#pragma unroll
        for (int nte = 0; nte < 8; ++nte) acc[mt][nte][j] *= sf;
        int qr = mt * 16 + lg * 4 + j;
        int qx = (qr & 7) << 3;
#pragma unroll
        for (int nt = 0; nt < 4; ++nt)
          Pw[qr * 64 + ((nt * 16 + l15) ^ qx)] = bf16b(sc[mt][nt][j]);
      }
    }

    // PV: ctx[32q x 128e] += P[32q x 64s] * V[64s x 128e]
#pragma unroll
    for (int kk = 0; kk < 2; ++kk) {
      bf16x8 pa[2];
#pragma unroll
      for (int mt = 0; mt < 2; ++mt) {
        int qr = mt * 16 + l15;
        pa[mt] = *(const bf16x8*)&Pw[qr * 64 + ((lg * 8 + kk * 32) ^ ((qr & 7) << 3))];
      }
#pragma unroll
      for (int nte = 0; nte < 8; ++nte) {
        int e = nte * 16 + l15;
        bf16x8 vb = *(const bf16x8*)&Vs[e * 64 + ((lg * 8 + kk * 32) ^ ((e & 7) << 3))];
        acc[0][nte] = mfma16(pa[0], vb, acc[0][nte]);
        acc[1][nte] = mfma16(pa[1], vb, acc[1][nte]);
      }
    }
    __syncthreads();
  }

  // epilogue: normalize, write ctx as [b][l][h][e] bf16
  int b_ = bh >> 3, h_ = bh & 7;
#pragma unroll
  for (int mt = 0; mt < 2; ++mt) {
#pragma unroll
    for (int j = 0; j < 4; ++j) {
      int q = qbase + mt * 16 + lg * 4 + j;
      float inv = 1.0f / lrun[mt][j];
      short* orow = Ctx + (((size_t)b_ * 2048 + q) * 8 + h_) * 128;
#pragma unroll
      for (int nte = 0; nte < 8; ++nte)
        orow[nte * 16 + l15] = bf16b(acc[mt][nte][j] * inv);
    }
  }
}

// ---------- kernel 5: output projection, fp32 epilogue ----------
__global__ __launch_bounds__(256, 2) void gemm_out(const short* __restrict__ Ctx,
                                                   const short* __restrict__ WoT,
                                                   const float* __restrict__ bo,
                                                   float* __restrict__ Out) {
  __shared__ short As[8192], Bs[8192];
  int m0 = blockIdx.y * 128, n0 = blockIdx.x * 128;
  f32x4 acc[4][4];
#pragma unroll
  for (int mt = 0; mt < 4; ++mt)
#pragma unroll
    for (int nt = 0; nt < 4; ++nt) acc[mt][nt] = f32x4{0.f, 0.f, 0.f, 0.f};
  gemm_core(Ctx, WoT, m0, n0, As, Bs, acc);
  int lane = threadIdx.x & 63, wave = threadIdx.x >> 6;
  int wr = wave >> 1, wc = wave & 1, l15 = lane & 15, lg = lane >> 4;
#pragma unroll
  for (int mt = 0; mt < 4; ++mt)
#pragma unroll
    for (int nt = 0; nt < 4; ++nt) {
      int n = n0 + wc * 64 + nt * 16 + l15;
      float bb = bo[n];
#pragma unroll
      for (int j = 0; j < 4; ++j) {
        int m = m0 + wr * 64 + mt * 16 + lg * 4 + j;
        Out[(size_t)m * 1024 + n] = acc[mt][nt][j] + bb;
      }
    }
}

// ---------- host ----------
extern "C" void kernel_launch(void* const* d_in, const int* in_sizes, int n_in,
                              void* d_out, int out_size, void* d_ws, size_t ws_size,
                              hipStream_t stream) {
  const float* q = (const float*)d_in[0];
  const float* k = (const float*)d_in[1];
  const float* v = (const float*)d_in[2];
  const float* Wq = (const float*)d_in[3];
  const float* bq = (const float*)d_in[4];
  const float* Wk = (const float*)d_in[5];
  const float* bk = (const float*)d_in[6];
  const float* Wv = (const float*)d_in[7];
  const float* bv = (const float*)d_in[8];
  const float* Wo = (const float*)d_in[9];
  const float* bo = (const float*)d_in[10];
  float* out = (float*)d_out;

  short* ws = (short*)d_ws;
  short* X3 = ws;                               // 3 * 8388608 shorts
  short* WT = X3 + (size_t)3 * 8388608;         // 4 * 1048576 shorts
  short* Qg = WT + (size_t)4 * 1048576;         // 8388608 shorts each
  short* Kg = Qg + (size_t)8388608;
  short* Vtg = Kg + (size_t)8388608;
  short* Ctx = X3;  // X dead after gemm_qkv; reuse for attention output

  hipLaunchKernelGGL(cvt_x, dim3(8192, 3), dim3(256), 0, stream, q, k, v, X3);
  hipLaunchKernelGGL(cvt_w, dim3(16, 16, 4), dim3(256), 0, stream, Wq, Wk, Wv, Wo, WT);
  hipLaunchKernelGGL(gemm_qkv, dim3(8, 64, 3), dim3(256), 0, stream, X3, WT, bq, bk,
                     bv, Qg, Kg, Vtg);
  hipLaunchKernelGGL(attn, dim3(16, 32), dim3(256), 0, stream, Qg, Kg, Vtg, Ctx);
  hipLaunchKernelGGL(gemm_out, dim3(8, 64), dim3(256), 0, stream, Ctx,
                     WT + (size_t)3 * 1048576, bo, out);
}

// Round 2
// 223.647 us; speedup vs baseline: 1.2136x; 1.2136x over previous
//
#include <hip/hip_runtime.h>
#include <hip/hip_bf16.h>
#include <cstdint>

// ---------- types ----------
typedef __attribute__((ext_vector_type(4))) float f32x4;
typedef __attribute__((ext_vector_type(16))) float f32x16;
typedef __attribute__((ext_vector_type(8))) __bf16 bf16x8;
typedef __attribute__((ext_vector_type(4))) unsigned u32x4;

#define SCALE_Q 0.08838834764831845f  /* 1/sqrt(128) */

__device__ __forceinline__ short bf16b(float f) {
  unsigned u = __builtin_bit_cast(unsigned, f);
  unsigned r = (u + 0x7fffu + ((u >> 16) & 1u)) >> 16;
  return (short)r;
}

__device__ __forceinline__ unsigned packbf(float lo, float hi) {
  return (unsigned)(unsigned short)bf16b(lo) |
         ((unsigned)(unsigned short)bf16b(hi) << 16);
}

__device__ __forceinline__ f32x4 mfma16(bf16x8 a, bf16x8 b, f32x4 c) {
  return __builtin_amdgcn_mfma_f32_16x16x32_bf16(a, b, c, 0, 0, 0);
}
__device__ __forceinline__ f32x16 mfma32(bf16x8 a, bf16x8 b, f32x16 c) {
  return __builtin_amdgcn_mfma_f32_32x32x16_bf16(a, b, c, 0, 0, 0);
}

__device__ __forceinline__ void async16(void* lds, const void* g) {
  __builtin_amdgcn_global_load_lds(
      (const __attribute__((address_space(1))) unsigned int*)g,
      (__attribute__((address_space(3))) unsigned int*)lds, 16, 0, 0);
}

// ---------- kernel 1: fp32 -> bf16 for queries/keys/values ----------
__global__ void cvt_x(const float* __restrict__ q, const float* __restrict__ k,
                      const float* __restrict__ v, short* __restrict__ out) {
  const float* src = (blockIdx.y == 0) ? q : (blockIdx.y == 1 ? k : v);
  short* dst = out + (size_t)blockIdx.y * 8388608;
  size_t i = (size_t)blockIdx.x * 256 + threadIdx.x;
  float4 f = reinterpret_cast<const float4*>(src)[i];
  short4 o;
  o.x = bf16b(f.x); o.y = bf16b(f.y); o.z = bf16b(f.z); o.w = bf16b(f.w);
  reinterpret_cast<short4*>(dst)[i] = o;
}

// ---------- kernel 2: transpose + convert weights -> WT[z][N][K] bf16 ----------
__global__ void cvt_w(const float* __restrict__ Wq, const float* __restrict__ Wk,
                      const float* __restrict__ Wv, const float* __restrict__ Wo,
                      short* __restrict__ out) {
  int z = blockIdx.z;
  const float* W = (z == 0) ? Wq : (z == 1) ? Wk : (z == 2) ? Wv : Wo;
  float scale = (z == 0) ? SCALE_Q : 1.0f;
  __shared__ float t[64][65];
  int n0 = blockIdx.x * 64, k0 = blockIdx.y * 64;
  int c = threadIdx.x & 63, r0 = threadIdx.x >> 6;
#pragma unroll
  for (int rr = 0; rr < 16; ++rr) {
    int r = rr * 4 + r0;
    t[r][c] = W[(size_t)(k0 + r) * 1024 + n0 + c];
  }
  __syncthreads();
  short* dst = out + (size_t)z * 1048576;
#pragma unroll
  for (int rr = 0; rr < 16; ++rr) {
    int r = rr * 4 + r0;
    dst[(size_t)(n0 + r) * 1024 + k0 + c] = bf16b(t[c][r] * scale);
  }
}

// ---------- shared GEMM mainloop (m97 structure) ----------
__device__ __forceinline__ void gemm_core(const short* A, const short* Bn, int m0,
                                          int n0, short* As, short* Bs,
                                          f32x4 acc[4][4]) {
  int tid = threadIdx.x;
  int lane = tid & 63, wave = tid >> 6;
  int wr = wave >> 1, wc = wave & 1, l15 = lane & 15, lg = lane >> 4;
  for (int k0 = 0; k0 < 1024; k0 += 64) {
#pragma unroll
    for (int i = 0; i < 4; ++i) {
      int r = (tid >> 3) + i * 32, cb = (tid & 7) * 16;
      async16((char*)As + i * 4096 + tid * 16,
              (const char*)A + ((size_t)(m0 + r) * 1024 + k0) * 2 + cb);
      async16((char*)Bs + i * 4096 + tid * 16,
              (const char*)Bn + ((size_t)(n0 + r) * 1024 + k0) * 2 + cb);
    }
    __syncthreads();
#pragma unroll
    for (int kk = 0; kk < 2; ++kk) {
      bf16x8 a[4], b[4];
#pragma unroll
      for (int mt = 0; mt < 4; ++mt)
        a[mt] = *(const bf16x8*)&As[(wr * 64 + mt * 16 + l15) * 64 + lg * 8 + kk * 32];
#pragma unroll
      for (int nt = 0; nt < 4; ++nt)
        b[nt] = *(const bf16x8*)&Bs[(wc * 64 + nt * 16 + l15) * 64 + lg * 8 + kk * 32];
#pragma unroll
      for (int mt = 0; mt < 4; ++mt)
#pragma unroll
        for (int nt = 0; nt < 4; ++nt)
          acc[mt][nt] = mfma16(a[mt], b[nt], acc[mt][nt]);
    }
    __syncthreads();
  }
}

// ---------- kernel 3: QKV projection GEMMs ----------
// Epilogue layouts: Q [bh][l][e] linear;
// K  [bh][s][e ^ ((s&15)<<3)]  (A-frag swizzle for 32-row reads);
// Vt [bh][e][s ^ (((e>>1)&7)<<3)]  (paired-row LDS layout swizzle).
__global__ __launch_bounds__(256, 2) void gemm_qkv(
    const short* __restrict__ X3, const short* __restrict__ WT,
    const float* __restrict__ bq, const float* __restrict__ bk,
    const float* __restrict__ bv, short* __restrict__ Qg, short* __restrict__ Kg,
    short* __restrict__ Vtg) {
  __shared__ short As[8192], Bs[8192];
  int z = blockIdx.z;
  const short* A = X3 + (size_t)z * 8388608;
  const short* Bn = WT + (size_t)z * 1048576;
  const float* bias = (z == 0) ? bq : (z == 1) ? bk : bv;
  float bscale = (z == 0) ? SCALE_Q : 1.0f;
  int m0 = blockIdx.y * 128, n0 = blockIdx.x * 128;
  f32x4 acc[4][4];
#pragma unroll
  for (int mt = 0; mt < 4; ++mt)
#pragma unroll
    for (int nt = 0; nt < 4; ++nt) acc[mt][nt] = f32x4{0.f, 0.f, 0.f, 0.f};
  gemm_core(A, Bn, m0, n0, As, Bs, acc);
  int lane = threadIdx.x & 63, wave = threadIdx.x >> 6;
  int wr = wave >> 1, wc = wave & 1, l15 = lane & 15, lg = lane >> 4;
#pragma unroll
  for (int mt = 0; mt < 4; ++mt)
#pragma unroll
    for (int nt = 0; nt < 4; ++nt) {
      int n = n0 + wc * 64 + nt * 16 + l15;
      float bb = bias[n] * bscale;
#pragma unroll
      for (int j = 0; j < 4; ++j) {
        int m = m0 + wr * 64 + mt * 16 + lg * 4 + j;
        short o = bf16b(acc[mt][nt][j] + bb);
        int s_ = m & 2047, b_ = m >> 11, h_ = n >> 7, e_ = n & 127;
        size_t bh = (size_t)b_ * 8 + h_;
        if (z == 0)
          Qg[(bh * 2048 + s_) * 128 + e_] = o;
        else if (z == 1)
          Kg[(bh * 2048 + s_) * 128 + (e_ ^ ((s_ & 15) << 3))] = o;
        else
          Vtg[(bh * 128 + e_) * 2048 + (s_ ^ (((e_ >> 1) & 7) << 3))] = o;
      }
    }
}

// ---------- kernel 4: flash attention, 32x32 swapped-QK^T, in-register P ----------
// 4 waves x 32 q-rows (QBLK=128), KVBLK=64, E=128.
// 2-phase pipeline: double-buffered K/V LDS, counted vmcnt, raw s_barrier.
__global__ __launch_bounds__(256, 2) void attn(const short* __restrict__ Qg,
                                               const short* __restrict__ Kg,
                                               const short* __restrict__ Vtg,
                                               short* __restrict__ Ctx) {
  __shared__ short Ks[2][8192];  // [64 s][128 e], e ^ ((s&15)<<3)
  __shared__ short Vs[2][8192];  // [64 r][(e&1)*64 + (s ^ ((r&7)<<3))], r=e>>1
  int tid = threadIdx.x;
  int lane = tid & 63, wave = tid >> 6;
  int l31 = lane & 31, h = lane >> 5;
  int bh = blockIdx.y, qb = blockIdx.x;
  int qbase = qb * 128 + wave * 32;
  const short* Qp = Qg + (size_t)bh * 2048 * 128;
  const char* Kbase = (const char*)(Kg + (size_t)bh * 2048 * 128);
  const char* Vbase = (const char*)(Vtg + (size_t)bh * 128 * 2048);

  auto stage = [&](int t, int buf) {
    int s0 = t * 64;
    char* kd = (char*)&Ks[buf][0];
    char* vd = (char*)&Vs[buf][0];
#pragma unroll
    for (int i = 0; i < 4; ++i)
      async16(kd + i * 4096 + tid * 16,
              Kbase + (size_t)s0 * 256 + i * 4096 + tid * 16);
#pragma unroll
    for (int i = 0; i < 4; ++i) {
      int e = i * 32 + 2 * (tid >> 4) + ((tid >> 3) & 1);
      async16(vd + i * 4096 + tid * 16,
              Vbase + (size_t)e * 4096 + s0 * 2 + (tid & 7) * 16);
    }
  };

  stage(0, 0);

  // Q fragments (B-operand): lane holds Q[qbase + l31][ksl*16 + h*8 + i]
  bf16x8 qa[8];
  const short* qrow = Qp + (size_t)(qbase + l31) * 128 + h * 8;
#pragma unroll
  for (int ksl = 0; ksl < 8; ++ksl) qa[ksl] = *(const bf16x8*)(qrow + ksl * 16);

  f32x16 acc[4];
#pragma unroll
  for (int i = 0; i < 4; ++i)
#pragma unroll
    for (int r = 0; r < 16; ++r) acc[i][r] = 0.f;
  float mrun = -1e30f, lrun = 0.f;

  int swK = (l31 & 15) << 3;
  int swV = ((l31 >> 1) & 7) << 3;

  for (int t = 0; t < 32; ++t) {
    int cur = t & 1;
    if (t < 31) {
      stage(t + 1, cur ^ 1);
      asm volatile("s_waitcnt vmcnt(8)" ::: "memory");
    } else {
      asm volatile("s_waitcnt vmcnt(0)" ::: "memory");
    }
    __builtin_amdgcn_s_barrier();

    const short* Kc = Ks[cur];
    const short* Vc = Vs[cur];

    // QK^T swapped: st[ts] = K_tile_ts . Q^T -> D[s][q], col=q=l31,
    // row s = ts*32 + (reg&3)+8*(reg>>2)+4*h
    f32x16 st0, st1;
#pragma unroll
    for (int r = 0; r < 16; ++r) { st0[r] = 0.f; st1[r] = 0.f; }
    __builtin_amdgcn_s_setprio(1);
#pragma unroll
    for (int ksl = 0; ksl < 8; ++ksl) {
      int col = (ksl * 16 + h * 8) ^ swK;
      bf16x8 ka0 = *(const bf16x8*)&Kc[l31 * 128 + col];
      bf16x8 ka1 = *(const bf16x8*)&Kc[(32 + l31) * 128 + col];
      st0 = mfma32(ka0, qa[ksl], st0);
      st1 = mfma32(ka1, qa[ksl], st1);
    }
    __builtin_amdgcn_s_setprio(0);

    // online softmax: lane owns q = l31 (32 of 64 s-values; partner has rest)
    float mx = st0[0];
#pragma unroll
    for (int r = 1; r < 16; ++r) mx = fmaxf(mx, st0[r]);
#pragma unroll
    for (int r = 0; r < 16; ++r) mx = fmaxf(mx, st1[r]);
    mx = fmaxf(mx, __shfl_xor(mx, 32));
    int skip = __all(mx - mrun <= 5.0f);  // T13 defer-rescale
    float mn = mrun, sf = 1.f;
    if (!skip) {
      mn = fmaxf(mrun, mx);
      sf = __expf(mrun - mn);
      mrun = mn;
    }
    float rs = 0.f;
#pragma unroll
    for (int r = 0; r < 16; ++r) { float p = __expf(st0[r] - mn); st0[r] = p; rs += p; }
#pragma unroll
    for (int r = 0; r < 16; ++r) { float p = __expf(st1[r] - mn); st1[r] = p; rs += p; }
    rs += __shfl_xor(rs, 32);
    if (!skip) {
      lrun = lrun * sf + rs;
#pragma unroll
      for (int reg = 0; reg < 16; ++reg) {
        float s4 = __shfl(sf, (reg & 3) + 8 * (reg >> 2) + 4 * h);
#pragma unroll
        for (int nte = 0; nte < 4; ++nte) acc[nte][reg] *= s4;
      }
    } else {
      lrun += rs;
    }

    // T12: pack P to bf16, permlane32_swap into PV A-fragments
    unsigned w0[8], w1[8];
#pragma unroll
    for (int m = 0; m < 8; ++m) {
      w0[m] = packbf(st0[2 * m], st0[2 * m + 1]);
      w1[m] = packbf(st1[2 * m], st1[2 * m + 1]);
    }
    bf16x8 pa[4];
#pragma unroll
    for (int ks = 0; ks < 4; ++ks) {
      const unsigned* w = (ks & 2) ? w1 : w0;
      int mb = (ks & 1) * 4;
      unsigned a0 = w[mb], b0 = w[mb + 2];
      unsigned a1 = w[mb + 1], b1 = w[mb + 3];
      asm volatile("v_permlane32_swap_b32 %0, %1" : "+v"(a0), "+v"(b0));
      asm volatile("v_permlane32_swap_b32 %0, %1" : "+v"(a1), "+v"(b1));
      u32x4 tt;
      tt[0] = a0; tt[1] = a1; tt[2] = b0; tt[3] = b1;
      pa[ks] = __builtin_bit_cast(bf16x8, tt);
    }

    // PV: acc[nte] += P . V  (B-frag from paired-row swizzled Vs)
    __builtin_amdgcn_s_setprio(1);
#pragma unroll
    for (int nte = 0; nte < 4; ++nte) {
      int rbase = (nte * 16 + (l31 >> 1)) * 128 + (lane & 1) * 64;
#pragma unroll
      for (int ks = 0; ks < 4; ++ks) {
        int colk = (ks * 16 + h * 8) ^ swV;
        bf16x8 vb = *(const bf16x8*)&Vc[rbase + colk];
        acc[nte] = mfma32(pa[ks], vb, acc[nte]);
      }
    }
    __builtin_amdgcn_s_setprio(0);
    __builtin_amdgcn_s_barrier();
  }

  // epilogue: normalize, write ctx as [b][l][h][e] bf16
  float inv = 1.0f / lrun;
  int b_ = bh >> 3, h_ = bh & 7;
#pragma unroll
  for (int reg = 0; reg < 16; ++reg) {
    int qr = (reg & 3) + 8 * (reg >> 2) + 4 * h;
    float iq = __shfl(inv, qr);
    int q = qbase + qr;
    short* orow = Ctx + (((size_t)b_ * 2048 + q) * 8 + h_) * 128;
#pragma unroll
    for (int nte = 0; nte < 4; ++nte)
      orow[nte * 32 + l31] = bf16b(acc[nte][reg] * iq);
  }
}

// ---------- kernel 5: output projection, fp32 epilogue ----------
__global__ __launch_bounds__(256, 2) void gemm_out(const short* __restrict__ Ctx,
                                                   const short* __restrict__ WoT,
                                                   const float* __restrict__ bo,
                                                   float* __restrict__ Out) {
  __shared__ short As[8192], Bs[8192];
  int m0 = blockIdx.y * 128, n0 = blockIdx.x * 128;
  f32x4 acc[4][4];
#pragma unroll
  for (int mt = 0; mt < 4; ++mt)
#pragma unroll
    for (int nt = 0; nt < 4; ++nt) acc[mt][nt] = f32x4{0.f, 0.f, 0.f, 0.f};
  gemm_core(Ctx, WoT, m0, n0, As, Bs, acc);
  int lane = threadIdx.x & 63, wave = threadIdx.x >> 6;
  int wr = wave >> 1, wc = wave & 1, l15 = lane & 15, lg = lane >> 4;
#pragma unroll
  for (int mt = 0; mt < 4; ++mt)
#pragma unroll
    for (int nt = 0; nt < 4; ++nt) {
      int n = n0 + wc * 64 + nt * 16 + l15;
      float bb = bo[n];
#pragma unroll
      for (int j = 0; j < 4; ++j) {
        int m = m0 + wr * 64 + mt * 16 + lg * 4 + j;
        Out[(size_t)m * 1024 + n] = acc[mt][nt][j] + bb;
      }
    }
}

// ---------- host ----------
extern "C" void kernel_launch(void* const* d_in, const int* in_sizes, int n_in,
                              void* d_out, int out_size, void* d_ws, size_t ws_size,
                              hipStream_t stream) {
  const float* q = (const float*)d_in[0];
  const float* k = (const float*)d_in[1];
  const float* v = (const float*)d_in[2];
  const float* Wq = (const float*)d_in[3];
  const float* bq = (const float*)d_in[4];
  const float* Wk = (const float*)d_in[5];
  const float* bk = (const float*)d_in[6];
  const float* Wv = (const float*)d_in[7];
  const float* bv = (const float*)d_in[8];
  const float* Wo = (const float*)d_in[9];
  const float* bo = (const float*)d_in[10];
  float* out = (float*)d_out;

  short* ws = (short*)d_ws;
  short* X3 = ws;                               // 3 * 8388608 shorts
  short* WT = X3 + (size_t)3 * 8388608;         // 4 * 1048576 shorts
  short* Qg = WT + (size_t)4 * 1048576;
  short* Kg = Qg + (size_t)8388608;
  short* Vtg = Kg + (size_t)8388608;
  short* Ctx = X3;  // X dead after gemm_qkv; reuse for attention output

  hipLaunchKernelGGL(cvt_x, dim3(8192, 3), dim3(256), 0, stream, q, k, v, X3);
  hipLaunchKernelGGL(cvt_w, dim3(16, 16, 4), dim3(256), 0, stream, Wq, Wk, Wv, Wo, WT);
  hipLaunchKernelGGL(gemm_qkv, dim3(8, 64, 3), dim3(256), 0, stream, X3, WT, bq, bk,
                     bv, Qg, Kg, Vtg);
  hipLaunchKernelGGL(attn, dim3(16, 32), dim3(256), 0, stream, Qg, Kg, Vtg, Ctx);
  hipLaunchKernelGGL(gemm_out, dim3(8, 64), dim3(256), 0, stream, Ctx,
                     WT + (size_t)3 * 1048576, bo, out);
}